// Round 4
// baseline (640.135 us; speedup 1.0000x reference)
//
#include <hip/hip_runtime.h>
#include <hip/hip_bf16.h>
#include <cstdint>
#include <cstddef>

// Problem constants
#define B_ 64
#define S_ 512
#define E_ 1024
#define H_ 16
#define D_ 64

typedef __attribute__((ext_vector_type(8))) short s8v;   // 8 bf16 = 4 VGPRs (A/B frag)
typedef __attribute__((ext_vector_type(4))) float f4v;   // C/D frag

__device__ __forceinline__ ushort f2bf(float f) {
  uint32_t u = __builtin_bit_cast(uint32_t, f);
  u += 0x7fffu + ((u >> 16) & 1u);   // RNE
  return (ushort)(u >> 16);
}

// async global->LDS, 16B per lane. LDS dest must be wave-uniform base + lane*16.
__device__ __forceinline__ void async_cp16(const void* g, void* l) {
  __builtin_amdgcn_global_load_lds(
      (const __attribute__((address_space(1))) unsigned int*)g,
      (__attribute__((address_space(3))) unsigned int*)(uintptr_t)l,
      16, 0, 0);
}

// ---------------- fp32 -> bf16 convert (X) ----------------
__global__ __launch_bounds__(256) void convertx(const float* __restrict__ X,
                                                ushort* __restrict__ Y) {
  size_t i = ((size_t)blockIdx.x * 256 + threadIdx.x) * 4;
  float4 v = *(const float4*)(X + i);
  uint2 p;
  p.x = (uint32_t)f2bf(v.x) | ((uint32_t)f2bf(v.y) << 16);
  p.y = (uint32_t)f2bf(v.z) | ((uint32_t)f2bf(v.w) << 16);
  *(uint2*)(Y + i) = p;
}

// ---------------- W (ExE fp32) -> Wt (ExE bf16, transposed) ----------------
__global__ __launch_bounds__(256) void transpose_w(const float* __restrict__ W,
                                                   ushort* __restrict__ Wt) {
  __shared__ ushort T[32][33];
  int x = threadIdx.x & 31, y = threadIdx.x >> 5;  // 32 x 8
  int c0 = blockIdx.x * 32;  // col base (n)
  int r0 = blockIdx.y * 32;  // row base (k)
#pragma unroll
  for (int i = 0; i < 4; i++) {
    int r = y + i * 8;
    T[x][r] = f2bf(W[(size_t)(r0 + r) * E_ + c0 + x]);  // coalesced read
  }
  __syncthreads();
#pragma unroll
  for (int i = 0; i < 4; i++) {
    int r = y + i * 8;
    Wt[(size_t)(c0 + r) * E_ + r0 + x] = T[r][x];  // coalesced write
  }
}

// ================= 256x256 4-phase GEMM core, [256][64] tiles =================
// C = A (MxK) * Bt^T (NxK), K = 1024, BK = 64. 512 threads = 8 waves (2M x 4N).
// Per-wave 128x64 output, acc[8][4].
// LDS: 2 buf x (A [256][64] 32KB + B [256][64] 32KB) = 128 KiB.
// Bank geometry = round-0 proven layout: 128 B row stride (all 32 banks/row),
// 16B chunk c of row r stored at slot c ^ (r&7)  (0.25 conflict-cyc/read
// measured vs 4.2 for the [256][32] 2-bit-XOR variant).
// Pipeline (counted vmcnt, full-tile staging):
//   prologue: STG tile0, tile1 (16 loads); vmcnt(8); bar
//   per t: ph1 {read kh0 m0-3 + b0; bar; MFMA16; bar}
//          ph2 {read kh0 m4-7;      bar; MFMA16; bar}
//          ph3 {read kh1 m0-3 + b1; bar; MFMA16; bar}
//          ph4 {read kh1 m4-7;      bar; MFMA16;
//               t<14: STG tile t+2 -> current buf (reads drained: post-MFMA,
//                     >=600cy before write can land); vmcnt(8) = t+1 landed
//               t==14: vmcnt(0) (tile 15 staged a full iter ago); bar}
//   Trailing barrier turns per-wave vmcnt into a cross-wave data guarantee.
__device__ __forceinline__ void gemm256_core(const ushort* __restrict__ A,
                                             const ushort* __restrict__ Bt,
                                             int m0, int n0, ushort* smem,
                                             f4v acc[8][4]) {
  const int tid = threadIdx.x;
  const int wave = tid >> 6, lane = tid & 63;
  const int wm = wave >> 2, wn = wave & 3;
  const int lrow = lane & 15, quad = lane >> 4;
  const int swl = lrow & 7;
  const int ch0 = (quad ^ swl) * 8;        // kh0 chunk (ushort offset)
  const int ch1 = ((4 + quad) ^ swl) * 8;  // kh1 chunk
  const int arow = (wm * 128 + lrow) * 64;
  const int brow = (wn * 64 + lrow) * 64;
  const int rr = tid >> 3;                            // staging row (0..63)
  const int sq = ((tid & 7) ^ (rr & 7)) * 8;          // pre-swizzled source chunk
  const ushort* Ab = A + (size_t)m0 * E_;
  const ushort* Bb = Bt + (size_t)n0 * E_;

#define SA_(buf) (smem + (buf) * 16384)
#define SB_(buf) (smem + 32768 + (buf) * 16384)

  auto STG = [&](const ushort* g, ushort* l) {      // one full [256][64] tile
#pragma unroll
    for (int i = 0; i < 4; i++)
      async_cp16(g + (size_t)(rr + i * 64) * E_ + sq, l + i * 4096 + tid * 8);
  };

#pragma unroll
  for (int i = 0; i < 8; i++)
#pragma unroll
    for (int j = 0; j < 4; j++) acc[i][j] = (f4v){0.f, 0.f, 0.f, 0.f};

  // prologue: tiles 0 and 1 (16 loads); wait oldest 8 (= tile 0).
  STG(Ab + 0, SA_(0));
  STG(Bb + 0, SB_(0));
  STG(Ab + 64, SA_(1));
  STG(Bb + 64, SB_(1));
  asm volatile("s_waitcnt vmcnt(8)" ::: "memory");
  __builtin_amdgcn_s_barrier();

  for (int t = 0; t < 16; ++t) {
    const int buf = t & 1;
    const ushort* As = SA_(buf);
    const ushort* Bs = SB_(buf);
    s8v a[4], b[4];

    // ---- phase 1: kh0, m0-3 ----
#pragma unroll
    for (int i = 0; i < 4; i++) a[i] = *(const s8v*)(As + arow + i * 1024 + ch0);
#pragma unroll
    for (int n = 0; n < 4; n++) b[n] = *(const s8v*)(Bs + brow + n * 1024 + ch0);
    __builtin_amdgcn_s_barrier();
    __builtin_amdgcn_s_setprio(1);
#pragma unroll
    for (int i = 0; i < 4; i++)
#pragma unroll
      for (int n = 0; n < 4; n++)
        acc[i][n] = __builtin_amdgcn_mfma_f32_16x16x32_bf16(a[i], b[n], acc[i][n], 0, 0, 0);
    __builtin_amdgcn_s_setprio(0);
    __builtin_amdgcn_s_barrier();

    // ---- phase 2: kh0, m4-7 (b reused) ----
#pragma unroll
    for (int i = 0; i < 4; i++) a[i] = *(const s8v*)(As + arow + (4 + i) * 1024 + ch0);
    __builtin_amdgcn_s_barrier();
    __builtin_amdgcn_s_setprio(1);
#pragma unroll
    for (int i = 0; i < 4; i++)
#pragma unroll
      for (int n = 0; n < 4; n++)
        acc[4 + i][n] = __builtin_amdgcn_mfma_f32_16x16x32_bf16(a[i], b[n], acc[4 + i][n], 0, 0, 0);
    __builtin_amdgcn_s_setprio(0);
    __builtin_amdgcn_s_barrier();

    // ---- phase 3: kh1, m0-3 ----
#pragma unroll
    for (int i = 0; i < 4; i++) a[i] = *(const s8v*)(As + arow + i * 1024 + ch1);
#pragma unroll
    for (int n = 0; n < 4; n++) b[n] = *(const s8v*)(Bs + brow + n * 1024 + ch1);
    __builtin_amdgcn_s_barrier();
    __builtin_amdgcn_s_setprio(1);
#pragma unroll
    for (int i = 0; i < 4; i++)
#pragma unroll
      for (int n = 0; n < 4; n++)
        acc[i][n] = __builtin_amdgcn_mfma_f32_16x16x32_bf16(a[i], b[n], acc[i][n], 0, 0, 0);
    __builtin_amdgcn_s_setprio(0);
    __builtin_amdgcn_s_barrier();

    // ---- phase 4: kh1, m4-7 (b reused) + stage t+2 + counted wait ----
#pragma unroll
    for (int i = 0; i < 4; i++) a[i] = *(const s8v*)(As + arow + (4 + i) * 1024 + ch1);
    __builtin_amdgcn_s_barrier();
    __builtin_amdgcn_s_setprio(1);
#pragma unroll
    for (int i = 0; i < 4; i++)
#pragma unroll
      for (int n = 0; n < 4; n++)
        acc[4 + i][n] = __builtin_amdgcn_mfma_f32_16x16x32_bf16(a[i], b[n], acc[4 + i][n], 0, 0, 0);
    __builtin_amdgcn_s_setprio(0);
    if (t < 14) {
      STG(Ab + (size_t)(t + 2) * 64, SA_(buf));   // buf(t+2)==buf(t); reads drained
      STG(Bb + (size_t)(t + 2) * 64, SB_(buf));
      asm volatile("s_waitcnt vmcnt(8)" ::: "memory");  // tile t+1 landed
    } else if (t == 14) {
      asm volatile("s_waitcnt vmcnt(0)" ::: "memory");  // tile 15 landed
    }
    __builtin_amdgcn_s_barrier();
  }
#undef SA_
#undef SB_
}

// ---------------- fused QKV GEMM: [32768,1024] x [3072,1024]^T ----------------
// Bt rows 0..1023 = Wq^T, 1024..2047 = Wk^T, 2048..3071 = Wv^T.
// 1536 blocks (12 n-tiles x 128 m-tiles), XCD-swizzled, n fastest.
// Q,K written [bh][s][d]; V written TRANSPOSED [bh][d][s].
__global__ __launch_bounds__(512, 2) void gemm_qkv(
    const ushort* __restrict__ A, const ushort* __restrict__ Bt,
    ushort* __restrict__ Qo, ushort* __restrict__ Ko, ushort* __restrict__ Vt) {
  __shared__ __align__(16) ushort smem[65536];  // 128 KiB
  const int orig = blockIdx.x;
  const int swz = (orig & 7) * 192 + (orig >> 3);  // 1536 % 8 == 0 -> bijective
  const int ntile = swz % 12, mtile = swz / 12;
  const int n0 = ntile * 256, m0 = mtile * 256;

  f4v acc[8][4];
  gemm256_core(A, Bt, m0, n0, smem, acc);

  const int tid = threadIdx.x;
  const int wave = tid >> 6, lane = tid & 63;
  const int wm = wave >> 2, wn = wave & 3;
  const int lrow = lane & 15, quad = lane >> 4;
  const int proj = n0 >> 10;       // 0=Q 1=K 2=V (uniform per block)
  const int np0 = n0 & 1023;
  const int hb = np0 >> 6;         // head base (0,4,8,12)
  const int bb = m0 >> 9, s0 = m0 & 511;

  if (proj < 2) {
    ushort* C = proj == 0 ? Qo : Ko;
    // two m-half steps: stage [128][264] rows, then 16B merged-head stores
#pragma unroll
    for (int h = 0; h < 2; h++) {
#pragma unroll
      for (int mf = 0; mf < 4; mf++)
#pragma unroll
        for (int n = 0; n < 4; n++)
#pragma unroll
          for (int r = 0; r < 4; r++)
            smem[(wm * 64 + mf * 16 + quad * 4 + r) * 264 + wn * 64 + n * 16 + lrow] =
                f2bf(acc[h * 4 + mf][n][r]);
      __syncthreads();
#pragma unroll
      for (int j = 0; j < 8; j++) {
        int chunk = j * 512 + tid;
        int pr = chunk >> 5, cc = chunk & 31;
        int s = s0 + (pr >> 6) * 128 + h * 64 + (pr & 63);
        int hd = hb + (cc >> 3);
        size_t off = (((size_t)bb * H_ + hd) * S_ + s) * D_ + (cc & 7) * 8;
        *(uint4*)&C[off] = *(const uint4*)&smem[pr * 264 + cc * 8];
      }
      if (h == 0) __syncthreads();
    }
  } else {
    // V transposed: two wm-half steps; stage [256 d][136] (s cols), 16B stores
#pragma unroll
    for (int w = 0; w < 2; w++) {
      if (wm == w) {
#pragma unroll
        for (int m = 0; m < 8; m++)
#pragma unroll
          for (int n = 0; n < 4; n++) {
            ushort4 pk;
            pk.x = f2bf(acc[m][n][0]);
            pk.y = f2bf(acc[m][n][1]);
            pk.z = f2bf(acc[m][n][2]);
            pk.w = f2bf(acc[m][n][3]);
            *(ushort4*)&smem[(wn * 64 + n * 16 + lrow) * 136 + m * 16 + quad * 4] = pk;
          }
      }
      __syncthreads();
#pragma unroll
      for (int j = 0; j < 8; j++) {
        int chunk = j * 512 + tid;
        int dr = chunk >> 4, cc = chunk & 15;
        int hd = hb + (dr >> 6), d = dr & 63;
        size_t off = (((size_t)bb * H_ + hd) * D_ + d) * S_ + s0 + w * 128 + cc * 8;
        *(uint4*)&Vt[off] = *(const uint4*)&smem[dr * 136 + cc * 8];
      }
      if (w == 0) __syncthreads();
    }
  }
}

// ---------------- O GEMM: fp32 out + bias ----------------
// 512 blocks (4 n-tiles x 128 m-tiles), XCD-swizzled.
__global__ __launch_bounds__(512, 2) void gemm_o(
    const ushort* __restrict__ A, const ushort* __restrict__ Bt,
    float* __restrict__ C, const float* __restrict__ bias) {
  __shared__ __align__(16) ushort smem[65536];
  const int orig = blockIdx.x;
  const int swz = (orig & 7) * 64 + (orig >> 3);  // 512 % 8 == 0 -> bijective
  const int ntile = swz & 3, mtile = swz >> 2;
  const int n0 = ntile * 256, m0 = mtile * 256;

  f4v acc[8][4];
  gemm256_core(A, Bt, m0, n0, smem, acc);

  const int tid = threadIdx.x;
  const int wave = tid >> 6, lane = tid & 63;
  const int wm = wave >> 2, wn = wave & 3;
  const int lrow = lane & 15, quad = lane >> 4;
#pragma unroll
  for (int n = 0; n < 4; n++) {
    int col = n0 + wn * 64 + n * 16 + lrow;
    float bv = bias[col];
#pragma unroll
    for (int m = 0; m < 8; m++) {
      int row = m0 + wm * 128 + m * 16 + quad * 4;
#pragma unroll
      for (int r = 0; r < 4; r++)
        C[(size_t)(row + r) * E_ + col] = acc[m][n][r] + bv;
    }
  }
}

// ---------------- fused causal flash attention v3 ----------------
// grid: (4, B*H). block: 256 (4 waves). Block qp pairs q-tiles (qp, 7-qp):
// wave w owns 16-row m-tile mi=0 at qp*64+w*16 and mi=1 at (7-qp)*64+w*16
// -> every wave does exactly 9 mi-tile-units (causal-balanced).
// K/V cooperatively staged to double-buffered LDS; stage t+1 issued BEFORE
// compute(t), single __syncthreads (vmcnt drain) after compute -> loads fly
// under compute (T3-lite 2-phase).
// QK^T SWAPPED (mfma(K,Q)): S^T[k=quad*4+r + ni*16][q=lrow] -> row stats are
// 15 in-lane ops + 2 shuffles; m/l per-lane scalars. P written transposed to
// per-wave LDS (layout identical to before for the PV A-frag read).
__global__ __launch_bounds__(256, 3) void attn_kernel(
    const ushort* __restrict__ Qg, const ushort* __restrict__ Kg,
    const ushort* __restrict__ Vtg, ushort* __restrict__ AO) {
  __shared__ __align__(16) ushort Ks[2][64 * 64];
  __shared__ __align__(16) ushort Vts[2][64 * 64];   // [d][s_local]
  __shared__ __align__(16) ushort Ps[4][32 * 72];    // per-wave P / O staging

  const int qp = blockIdx.x;            // 0..3 -> q-tiles qp and 7-qp
  const int bh = blockIdx.y;            // 0..1023
  const int b = bh >> 4, h = bh & 15;
  const int tid = threadIdx.x, wave = tid >> 6, lane = tid & 63;
  const int lrow = lane & 15, quad = lane >> 4;
  const int swl = lrow & 7;
  const size_t base = (size_t)bh * (S_ * D_);
  const int qB0 = qp * 64 + wave * 16;        // mi=0 q-rows
  const int qB1 = (7 - qp) * 64 + wave * 16;  // mi=1 q-rows
  const int kd0 = qp, kd1 = 7 - qp;           // per-mi diagonal K-tile
  const int NT = kd1 + 1;

  // Q fragments straight from global (B-frag: col=q-row=lrow, k=quad*8 in 32)
  s8v qf[2][2];
#pragma unroll
  for (int kk = 0; kk < 2; kk++) {
    qf[0][kk] = *(const s8v*)(Qg + base + (size_t)(qB0 + lrow) * 64 + kk * 32 + quad * 8);
    qf[1][kk] = *(const s8v*)(Qg + base + (size_t)(qB1 + lrow) * 64 + kk * 32 + quad * 8);
  }

  f4v o[2][4];
#pragma unroll
  for (int mi = 0; mi < 2; mi++)
#pragma unroll
    for (int di = 0; di < 4; di++) o[mi][di] = (f4v){0.f, 0.f, 0.f, 0.f};
  float mr[2] = {-INFINITY, -INFINITY};   // per-lane scalar (q-row = lrow)
  float lr[2] = {0.f, 0.f};

  ushort* pw = &Ps[wave][0];

  auto STAGE = [&](int kt, int bf) {
#pragma unroll
    for (int i = 0; i < 2; i++) {
      int c = i * 256 + tid;
      int r = c >> 3, cc = c & 7;
      int sc = cc ^ (r & 7);
      async_cp16(Kg + base + (size_t)(kt * 64 + r) * 64 + sc * 8, (void*)&Ks[bf][c * 8]);
    }
#pragma unroll
    for (int i = 0; i < 2; i++) {
      int c = i * 256 + tid;
      int d = c >> 3, cc = c & 7;
      int sc = cc ^ (d & 7);
      async_cp16(Vtg + base + (size_t)d * S_ + kt * 64 + sc * 8, (void*)&Vts[bf][c * 8]);
    }
  };

  STAGE(0, 0);
  __syncthreads();

  int buf = 0;
  for (int kt = 0; kt < NT; kt++) {
    if (kt + 1 < NT) STAGE(kt + 1, buf ^ 1);   // flies under compute
    const bool act0 = (kt <= kd0);             // wave-uniform
    const ushort* Kb = &Ks[buf][0];
    const ushort* Vb = &Vts[buf][0];

    // QK^T swapped: st[mi][ni][r] = S^T[k = kt*64+ni*16+quad*4+r][q = qB+lrow]
    f4v st[2][4];
#pragma unroll
    for (int mi = 0; mi < 2; mi++)
#pragma unroll
      for (int ni = 0; ni < 4; ni++) st[mi][ni] = (f4v){0.f, 0.f, 0.f, 0.f};
    __builtin_amdgcn_s_setprio(1);
#pragma unroll
    for (int kk = 0; kk < 2; kk++) {
      const int ch = (kk * 4 + quad) ^ swl;
#pragma unroll
      for (int ni = 0; ni < 4; ni++) {
        s8v kf = *(const s8v*)&Kb[(ni * 16 + lrow) * 64 + ch * 8];
        st[1][ni] = __builtin_amdgcn_mfma_f32_16x16x32_bf16(kf, qf[1][kk], st[1][ni], 0, 0, 0);
        if (act0)
          st[0][ni] = __builtin_amdgcn_mfma_f32_16x16x32_bf16(kf, qf[0][kk], st[0][ni], 0, 0, 0);
      }
    }
    __builtin_amdgcn_s_setprio(0);

    // softmax per mi; P -> per-wave LDS (transposed write: row q=lrow)
    float alr[2][4];
#pragma unroll
    for (int mi = 0; mi < 2; mi++) {
      if (mi == 0 && !act0) continue;
      const int qB = mi ? qB1 : qB0;
      if (kt == (mi ? kd1 : kd0)) {   // diagonal tile: mask k > q
        int qrow = qB + lrow;
#pragma unroll
        for (int ni = 0; ni < 4; ni++) {
          int kc0 = kt * 64 + ni * 16 + quad * 4;
#pragma unroll
          for (int r = 0; r < 4; r++)
            if (kc0 + r > qrow) st[mi][ni][r] = -INFINITY;
        }
      }
      // row max: 16 in-lane values, then cross-quad
      float bm = st[mi][0][0];
#pragma unroll
      for (int ni = 0; ni < 4; ni++)
#pragma unroll
        for (int r = 0; r < 4; r++) bm = fmaxf(bm, st[mi][ni][r]);
      bm = fmaxf(bm, __shfl_xor(bm, 16));
      bm = fmaxf(bm, __shfl_xor(bm, 32));
      float mn = fmaxf(mr[mi], bm);
      float al = __expf(mr[mi] - mn);
      mr[mi] = mn;
      float bs = 0.f;
#pragma unroll
      for (int ni = 0; ni < 4; ni++) {
        float p0 = __expf(st[mi][ni][0] - mn);
        float p1 = __expf(st[mi][ni][1] - mn);
        float p2 = __expf(st[mi][ni][2] - mn);
        float p3 = __expf(st[mi][ni][3] - mn);
        bs += (p0 + p1) + (p2 + p3);
        ushort4 pk = {f2bf(p0), f2bf(p1), f2bf(p2), f2bf(p3)};
        *(ushort4*)&pw[(mi * 16 + lrow) * 72 + ni * 16 + quad * 4] = pk;
      }
      bs += __shfl_xor(bs, 16);
      bs += __shfl_xor(bs, 32);
      lr[mi] = lr[mi] * al + bs;
      // redistribute al to this lane's o-rows (q-local = quad*4+r)
#pragma unroll
      for (int r = 0; r < 4; r++) alr[mi][r] = __shfl(al, (lane & 48) + quad * 4 + r);
#pragma unroll
      for (int di = 0; di < 4; di++)
#pragma unroll
        for (int r = 0; r < 4; r++) o[mi][di][r] *= alr[mi][r];
    }

    // PV: P as A-frag (wave-local LDS roundtrip), V as B-frag (swizzled)
    __builtin_amdgcn_s_setprio(1);
#pragma unroll
    for (int kk = 0; kk < 2; kk++) {
      const int ch = (kk * 4 + quad) ^ swl;
      s8v pf1 = *(const s8v*)&pw[(16 + lrow) * 72 + kk * 32 + quad * 8];
      if (act0) {
        s8v pf0 = *(const s8v*)&pw[lrow * 72 + kk * 32 + quad * 8];
#pragma unroll
        for (int di = 0; di < 4; di++) {
          s8v vf = *(const s8v*)&Vb[(di * 16 + lrow) * 64 + ch * 8];
          o[1][di] = __builtin_amdgcn_mfma_f32_16x16x32_bf16(pf1, vf, o[1][di], 0, 0, 0);
          o[0][di] = __builtin_amdgcn_mfma_f32_16x16x32_bf16(pf0, vf, o[0][di], 0, 0, 0);
        }
      } else {
#pragma unroll
        for (int di = 0; di < 4; di++) {
          s8v vf = *(const s8v*)&Vb[(di * 16 + lrow) * 64 + ch * 8];
          o[1][di] = __builtin_amdgcn_mfma_f32_16x16x32_bf16(pf1, vf, o[1][di], 0, 0, 0);
        }
      }
    }
    __builtin_amdgcn_s_setprio(0);

    __syncthreads();   // drains staging vmcnt + all waves done reading buf
    buf ^= 1;
  }

  // normalize: lr lives at lanes with lrow == q-local; redistribute to o-rows
  float inv[2][4];
#pragma unroll
  for (int mi = 0; mi < 2; mi++)
#pragma unroll
    for (int r = 0; r < 4; r++)
      inv[mi][r] = 1.0f / __shfl(lr[mi], (lane & 48) + quad * 4 + r);

#pragma unroll
  for (int mi = 0; mi < 2; mi++)
#pragma unroll
    for (int di = 0; di < 4; di++)
#pragma unroll
      for (int r = 0; r < 4; r++)
        pw[(mi * 16 + quad * 4 + r) * 72 + di * 16 + lrow] = f2bf(o[mi][di][r] * inv[mi][r]);

#pragma unroll
  for (int i = 0; i < 4; i++) {
    int c = i * 64 + lane;
    int row = c >> 3, cc = c & 7;
    uint4 val = *(const uint4*)&pw[row * 72 + cc * 8];
    int q = ((row >> 4) ? qB1 : qB0) + (row & 15);
    size_t off = ((size_t)b * S_ + q) * E_ + h * 64 + cc * 8;
    *(uint4*)&AO[off] = val;
  }
}

// ---------------- launch ----------------
extern "C" void kernel_launch(void* const* d_in, const int* in_sizes, int n_in,
                              void* d_out, int out_size, void* d_ws, size_t ws_size,
                              hipStream_t stream) {
  const float* X = (const float*)d_in[0];
  const float* Wq = (const float*)d_in[1];
  const float* Wk = (const float*)d_in[2];
  const float* Wv = (const float*)d_in[3];
  const float* Wo = (const float*)d_in[4];
  const float* bo = (const float*)d_in[5];
  float* out = (float*)d_out;

  // ws layout (bytes). AO aliases Xb (Xb dead after QKV GEMM). Total ~277 MB.
  char* ws = (char*)d_ws;
  ushort* Xb = (ushort*)(ws);                      //  67,108,864
  ushort* Wqkvt = (ushort*)(ws + 67108864);        //   6,291,456 (Wq^T|Wk^T|Wv^T)
  ushort* Wot = (ushort*)(ws + 73400320);          //   2,097,152
  ushort* Qb = (ushort*)(ws + 75497472);           //  67,108,864
  ushort* Kb = (ushort*)(ws + 142606336);          //  67,108,864
  ushort* Vtb = (ushort*)(ws + 209715200);         //  67,108,864 ([bh][d][s])
  ushort* AO = Xb;

  convertx<<<32768, 256, 0, stream>>>(X, Xb);
  transpose_w<<<dim3(32, 32), 256, 0, stream>>>(Wq, Wqkvt);
  transpose_w<<<dim3(32, 32), 256, 0, stream>>>(Wk, Wqkvt + 1024 * 1024);
  transpose_w<<<dim3(32, 32), 256, 0, stream>>>(Wv, Wqkvt + 2 * 1024 * 1024);
  transpose_w<<<dim3(32, 32), 256, 0, stream>>>(Wo, Wot);

  gemm_qkv<<<1536, 512, 0, stream>>>(Xb, Wqkvt, Qb, Kb, Vtb);

  attn_kernel<<<dim3(4, 1024), 256, 0, stream>>>(Qb, Kb, Vtb, AO);

  gemm_o<<<512, 512, 0, stream>>>(AO, Wot, out, bo);
}

// Round 5
// 626.326 us; speedup vs baseline: 1.0220x; 1.0220x over previous
//
#include <hip/hip_runtime.h>
#include <hip/hip_bf16.h>
#include <cstdint>
#include <cstddef>

// Problem constants
#define B_ 64
#define S_ 512
#define E_ 1024
#define H_ 16
#define D_ 64

typedef __attribute__((ext_vector_type(8))) short s8v;   // 8 bf16 = 4 VGPRs (A/B frag)
typedef __attribute__((ext_vector_type(4))) float f4v;   // C/D frag

__device__ __forceinline__ ushort f2bf(float f) {
  uint32_t u = __builtin_bit_cast(uint32_t, f);
  u += 0x7fffu + ((u >> 16) & 1u);   // RNE
  return (ushort)(u >> 16);
}

// async global->LDS, 16B per lane. LDS dest must be wave-uniform base + lane*16.
__device__ __forceinline__ void async_cp16(const void* g, void* l) {
  __builtin_amdgcn_global_load_lds(
      (const __attribute__((address_space(1))) unsigned int*)g,
      (__attribute__((address_space(3))) unsigned int*)(uintptr_t)l,
      16, 0, 0);
}

// ---------------- fp32 -> bf16 convert (X) ----------------
__global__ __launch_bounds__(256) void convertx(const float* __restrict__ X,
                                                ushort* __restrict__ Y) {
  size_t i = ((size_t)blockIdx.x * 256 + threadIdx.x) * 4;
  float4 v = *(const float4*)(X + i);
  uint2 p;
  p.x = (uint32_t)f2bf(v.x) | ((uint32_t)f2bf(v.y) << 16);
  p.y = (uint32_t)f2bf(v.z) | ((uint32_t)f2bf(v.w) << 16);
  *(uint2*)(Y + i) = p;
}

// ---------------- W (ExE fp32) -> Wt (ExE bf16, transposed) ----------------
__global__ __launch_bounds__(256) void transpose_w(const float* __restrict__ W,
                                                   ushort* __restrict__ Wt) {
  __shared__ ushort T[32][33];
  int x = threadIdx.x & 31, y = threadIdx.x >> 5;  // 32 x 8
  int c0 = blockIdx.x * 32;  // col base (n)
  int r0 = blockIdx.y * 32;  // row base (k)
#pragma unroll
  for (int i = 0; i < 4; i++) {
    int r = y + i * 8;
    T[x][r] = f2bf(W[(size_t)(r0 + r) * E_ + c0 + x]);  // coalesced read
  }
  __syncthreads();
#pragma unroll
  for (int i = 0; i < 4; i++) {
    int r = y + i * 8;
    Wt[(size_t)(c0 + r) * E_ + r0 + x] = T[r][x];  // coalesced write
  }
}

// ================= 256x256 4-phase GEMM core, [256][64] tiles =================
// C = A (MxK) * Bt^T (NxK), K = 1024, BK = 64. 512 threads = 8 waves (2M x 4N).
// Per-wave 128x64 output, acc[8][4].
// LDS: 2 buf x (A [256][64] 32KB + B [256][64] 32KB) = 128 KiB.
// Bank geometry (kept from r4, conflicts 19.7M -> 0.79M): 128 B row stride,
// 16B chunk c of row r stored at slot c ^ (r&7).
// Staging (restored r3-style spread, distance-1, issue-early/drain-late):
//   ph1: issue all 4 A(t+1) loads -> buf^1   (its t-1 readers finished 2 bars ago)
//   ph2: issue all 4 B(t+1) loads -> buf^1
//   ph4 end: vmcnt(0)  -- youngest load is 2 full phases (~1000+cyc) old ->
//            drain ~free; own-wave vmcnt + shared barrier = cross-wave guarantee.
// r4's clustered ph4-issue burst caused FETCH +30% (L2 thrash) and stalls.
__device__ __forceinline__ void gemm256_core(const ushort* __restrict__ A,
                                             const ushort* __restrict__ Bt,
                                             int m0, int n0, ushort* smem,
                                             f4v acc[8][4]) {
  const int tid = threadIdx.x;
  const int wave = tid >> 6, lane = tid & 63;
  const int wm = wave >> 2, wn = wave & 3;
  const int lrow = lane & 15, quad = lane >> 4;
  const int swl = lrow & 7;
  const int ch0 = (quad ^ swl) * 8;        // kh0 chunk (ushort offset)
  const int ch1 = ((4 + quad) ^ swl) * 8;  // kh1 chunk
  const int arow = (wm * 128 + lrow) * 64;
  const int brow = (wn * 64 + lrow) * 64;
  const int rr = tid >> 3;                            // staging row (0..63)
  const int sq = ((tid & 7) ^ (rr & 7)) * 8;          // pre-swizzled source chunk
  const ushort* Ab = A + (size_t)m0 * E_;
  const ushort* Bb = Bt + (size_t)n0 * E_;

#define SA_(buf) (smem + (buf) * 16384)
#define SB_(buf) (smem + 32768 + (buf) * 16384)

  auto STG = [&](const ushort* g, ushort* l) {      // one full [256][64] tile
#pragma unroll
    for (int i = 0; i < 4; i++)
      async_cp16(g + (size_t)(rr + i * 64) * E_ + sq, l + i * 4096 + tid * 8);
  };

#pragma unroll
  for (int i = 0; i < 8; i++)
#pragma unroll
    for (int j = 0; j < 4; j++) acc[i][j] = (f4v){0.f, 0.f, 0.f, 0.f};

  // prologue: tile 0 only (8 loads); drain; bar.
  STG(Ab + 0, SA_(0));
  STG(Bb + 0, SB_(0));
  asm volatile("s_waitcnt vmcnt(0)" ::: "memory");
  __builtin_amdgcn_s_barrier();

  for (int t = 0; t < 16; ++t) {
    const int buf = t & 1;
    const ushort* As = SA_(buf);
    const ushort* Bs = SB_(buf);
    ushort* An = SA_(buf ^ 1);
    ushort* Bn = SB_(buf ^ 1);
    s8v a[4], b[4];

    // ---- phase 1: kh0, m0-3; issue A(t+1) ----
#pragma unroll
    for (int i = 0; i < 4; i++) a[i] = *(const s8v*)(As + arow + i * 1024 + ch0);
#pragma unroll
    for (int n = 0; n < 4; n++) b[n] = *(const s8v*)(Bs + brow + n * 1024 + ch0);
    if (t < 15) STG(Ab + (size_t)(t + 1) * 64, An);
    __builtin_amdgcn_s_barrier();
    __builtin_amdgcn_s_setprio(1);
#pragma unroll
    for (int i = 0; i < 4; i++)
#pragma unroll
      for (int n = 0; n < 4; n++)
        acc[i][n] = __builtin_amdgcn_mfma_f32_16x16x32_bf16(a[i], b[n], acc[i][n], 0, 0, 0);
    __builtin_amdgcn_s_setprio(0);
    __builtin_amdgcn_s_barrier();

    // ---- phase 2: kh0, m4-7 (b reused); issue B(t+1) ----
#pragma unroll
    for (int i = 0; i < 4; i++) a[i] = *(const s8v*)(As + arow + (4 + i) * 1024 + ch0);
    if (t < 15) STG(Bb + (size_t)(t + 1) * 64, Bn);
    __builtin_amdgcn_s_barrier();
    __builtin_amdgcn_s_setprio(1);
#pragma unroll
    for (int i = 0; i < 4; i++)
#pragma unroll
      for (int n = 0; n < 4; n++)
        acc[4 + i][n] = __builtin_amdgcn_mfma_f32_16x16x32_bf16(a[i], b[n], acc[4 + i][n], 0, 0, 0);
    __builtin_amdgcn_s_setprio(0);
    __builtin_amdgcn_s_barrier();

    // ---- phase 3: kh1, m0-3 ----
#pragma unroll
    for (int i = 0; i < 4; i++) a[i] = *(const s8v*)(As + arow + i * 1024 + ch1);
#pragma unroll
    for (int n = 0; n < 4; n++) b[n] = *(const s8v*)(Bs + brow + n * 1024 + ch1);
    __builtin_amdgcn_s_barrier();
    __builtin_amdgcn_s_setprio(1);
#pragma unroll
    for (int i = 0; i < 4; i++)
#pragma unroll
      for (int n = 0; n < 4; n++)
        acc[i][n] = __builtin_amdgcn_mfma_f32_16x16x32_bf16(a[i], b[n], acc[i][n], 0, 0, 0);
    __builtin_amdgcn_s_setprio(0);
    __builtin_amdgcn_s_barrier();

    // ---- phase 4: kh1, m4-7 (b reused); late drain ----
#pragma unroll
    for (int i = 0; i < 4; i++) a[i] = *(const s8v*)(As + arow + (4 + i) * 1024 + ch1);
    __builtin_amdgcn_s_barrier();
    __builtin_amdgcn_s_setprio(1);
#pragma unroll
    for (int i = 0; i < 4; i++)
#pragma unroll
      for (int n = 0; n < 4; n++)
        acc[4 + i][n] = __builtin_amdgcn_mfma_f32_16x16x32_bf16(a[i], b[n], acc[4 + i][n], 0, 0, 0);
    __builtin_amdgcn_s_setprio(0);
    if (t < 15) asm volatile("s_waitcnt vmcnt(0)" ::: "memory");  // t+1 landed (issued 2 phases ago)
    __builtin_amdgcn_s_barrier();
  }
#undef SA_
#undef SB_
}

// ---------------- fused QKV GEMM: [32768,1024] x [3072,1024]^T ----------------
// Bt rows 0..1023 = Wq^T, 1024..2047 = Wk^T, 2048..3071 = Wv^T.
// 1536 blocks (12 n-tiles x 128 m-tiles), XCD-swizzled, n fastest.
// Q,K written [bh][s][d]; V written TRANSPOSED [bh][d][s].
__global__ __launch_bounds__(512, 2) void gemm_qkv(
    const ushort* __restrict__ A, const ushort* __restrict__ Bt,
    ushort* __restrict__ Qo, ushort* __restrict__ Ko, ushort* __restrict__ Vt) {
  __shared__ __align__(16) ushort smem[65536];  // 128 KiB
  const int orig = blockIdx.x;
  const int swz = (orig & 7) * 192 + (orig >> 3);  // 1536 % 8 == 0 -> bijective
  const int ntile = swz % 12, mtile = swz / 12;
  const int n0 = ntile * 256, m0 = mtile * 256;

  f4v acc[8][4];
  gemm256_core(A, Bt, m0, n0, smem, acc);

  const int tid = threadIdx.x;
  const int wave = tid >> 6, lane = tid & 63;
  const int wm = wave >> 2, wn = wave & 3;
  const int lrow = lane & 15, quad = lane >> 4;
  const int proj = n0 >> 10;       // 0=Q 1=K 2=V (uniform per block)
  const int np0 = n0 & 1023;
  const int hb = np0 >> 6;         // head base (0,4,8,12)
  const int bb = m0 >> 9, s0 = m0 & 511;

  if (proj < 2) {
    ushort* C = proj == 0 ? Qo : Ko;
    // two m-half steps: stage [128][264] rows, then 16B merged-head stores
#pragma unroll
    for (int h = 0; h < 2; h++) {
#pragma unroll
      for (int mf = 0; mf < 4; mf++)
#pragma unroll
        for (int n = 0; n < 4; n++)
#pragma unroll
          for (int r = 0; r < 4; r++)
            smem[(wm * 64 + mf * 16 + quad * 4 + r) * 264 + wn * 64 + n * 16 + lrow] =
                f2bf(acc[h * 4 + mf][n][r]);
      __syncthreads();
#pragma unroll
      for (int j = 0; j < 8; j++) {
        int chunk = j * 512 + tid;
        int pr = chunk >> 5, cc = chunk & 31;
        int s = s0 + (pr >> 6) * 128 + h * 64 + (pr & 63);
        int hd = hb + (cc >> 3);
        size_t off = (((size_t)bb * H_ + hd) * S_ + s) * D_ + (cc & 7) * 8;
        *(uint4*)&C[off] = *(const uint4*)&smem[pr * 264 + cc * 8];
      }
      if (h == 0) __syncthreads();
    }
  } else {
    // V transposed: two wm-half steps; stage [256 d][136] (s cols), 16B stores
#pragma unroll
    for (int w = 0; w < 2; w++) {
      if (wm == w) {
#pragma unroll
        for (int m = 0; m < 8; m++)
#pragma unroll
          for (int n = 0; n < 4; n++) {
            ushort4 pk;
            pk.x = f2bf(acc[m][n][0]);
            pk.y = f2bf(acc[m][n][1]);
            pk.z = f2bf(acc[m][n][2]);
            pk.w = f2bf(acc[m][n][3]);
            *(ushort4*)&smem[(wn * 64 + n * 16 + lrow) * 136 + m * 16 + quad * 4] = pk;
          }
      }
      __syncthreads();
#pragma unroll
      for (int j = 0; j < 8; j++) {
        int chunk = j * 512 + tid;
        int dr = chunk >> 4, cc = chunk & 15;
        int hd = hb + (dr >> 6), d = dr & 63;
        size_t off = (((size_t)bb * H_ + hd) * D_ + d) * S_ + s0 + w * 128 + cc * 8;
        *(uint4*)&Vt[off] = *(const uint4*)&smem[dr * 136 + cc * 8];
      }
      if (w == 0) __syncthreads();
    }
  }
}

// ---------------- O GEMM: fp32 out + bias ----------------
// 512 blocks (4 n-tiles x 128 m-tiles), XCD-swizzled.
__global__ __launch_bounds__(512, 2) void gemm_o(
    const ushort* __restrict__ A, const ushort* __restrict__ Bt,
    float* __restrict__ C, const float* __restrict__ bias) {
  __shared__ __align__(16) ushort smem[65536];
  const int orig = blockIdx.x;
  const int swz = (orig & 7) * 64 + (orig >> 3);  // 512 % 8 == 0 -> bijective
  const int ntile = swz & 3, mtile = swz >> 2;
  const int n0 = ntile * 256, m0 = mtile * 256;

  f4v acc[8][4];
  gemm256_core(A, Bt, m0, n0, smem, acc);

  const int tid = threadIdx.x;
  const int wave = tid >> 6, lane = tid & 63;
  const int wm = wave >> 2, wn = wave & 3;
  const int lrow = lane & 15, quad = lane >> 4;
#pragma unroll
  for (int n = 0; n < 4; n++) {
    int col = n0 + wn * 64 + n * 16 + lrow;
    float bv = bias[col];
#pragma unroll
    for (int m = 0; m < 8; m++) {
      int row = m0 + wm * 128 + m * 16 + quad * 4;
#pragma unroll
      for (int r = 0; r < 4; r++)
        C[(size_t)(row + r) * E_ + col] = acc[m][n][r] + bv;
    }
  }
}

// ---------------- fused causal flash attention v3 ----------------
// grid: (4, B*H). block: 256 (4 waves). Block qp pairs q-tiles (qp, 7-qp):
// wave w owns 16-row m-tile mi=0 at qp*64+w*16 and mi=1 at (7-qp)*64+w*16
// -> every wave does exactly 9 mi-tile-units (causal-balanced).
// K/V cooperatively staged to double-buffered LDS; stage t+1 issued BEFORE
// compute(t), single __syncthreads (vmcnt drain) after compute -> loads fly
// under compute (T3-lite 2-phase).
// QK^T SWAPPED (mfma(K,Q)): S^T[k=quad*4+r + ni*16][q=lrow] -> row stats are
// 15 in-lane ops + 2 shuffles; m/l per-lane scalars. P written transposed to
// per-wave LDS (layout identical to before for the PV A-frag read).
__global__ __launch_bounds__(256, 3) void attn_kernel(
    const ushort* __restrict__ Qg, const ushort* __restrict__ Kg,
    const ushort* __restrict__ Vtg, ushort* __restrict__ AO) {
  __shared__ __align__(16) ushort Ks[2][64 * 64];
  __shared__ __align__(16) ushort Vts[2][64 * 64];   // [d][s_local]
  __shared__ __align__(16) ushort Ps[4][32 * 72];    // per-wave P / O staging

  const int qp = blockIdx.x;            // 0..3 -> q-tiles qp and 7-qp
  const int bh = blockIdx.y;            // 0..1023
  const int b = bh >> 4, h = bh & 15;
  const int tid = threadIdx.x, wave = tid >> 6, lane = tid & 63;
  const int lrow = lane & 15, quad = lane >> 4;
  const int swl = lrow & 7;
  const size_t base = (size_t)bh * (S_ * D_);
  const int qB0 = qp * 64 + wave * 16;        // mi=0 q-rows
  const int qB1 = (7 - qp) * 64 + wave * 16;  // mi=1 q-rows
  const int kd0 = qp, kd1 = 7 - qp;           // per-mi diagonal K-tile
  const int NT = kd1 + 1;

  // Q fragments straight from global (B-frag: col=q-row=lrow, k=quad*8 in 32)
  s8v qf[2][2];
#pragma unroll
  for (int kk = 0; kk < 2; kk++) {
    qf[0][kk] = *(const s8v*)(Qg + base + (size_t)(qB0 + lrow) * 64 + kk * 32 + quad * 8);
    qf[1][kk] = *(const s8v*)(Qg + base + (size_t)(qB1 + lrow) * 64 + kk * 32 + quad * 8);
  }

  f4v o[2][4];
#pragma unroll
  for (int mi = 0; mi < 2; mi++)
#pragma unroll
    for (int di = 0; di < 4; di++) o[mi][di] = (f4v){0.f, 0.f, 0.f, 0.f};
  float mr[2] = {-INFINITY, -INFINITY};   // per-lane scalar (q-row = lrow)
  float lr[2] = {0.f, 0.f};

  ushort* pw = &Ps[wave][0];

  auto STAGE = [&](int kt, int bf) {
#pragma unroll
    for (int i = 0; i < 2; i++) {
      int c = i * 256 + tid;
      int r = c >> 3, cc = c & 7;
      int sc = cc ^ (r & 7);
      async_cp16(Kg + base + (size_t)(kt * 64 + r) * 64 + sc * 8, (void*)&Ks[bf][c * 8]);
    }
#pragma unroll
    for (int i = 0; i < 2; i++) {
      int c = i * 256 + tid;
      int d = c >> 3, cc = c & 7;
      int sc = cc ^ (d & 7);
      async_cp16(Vtg + base + (size_t)d * S_ + kt * 64 + sc * 8, (void*)&Vts[bf][c * 8]);
    }
  };

  STAGE(0, 0);
  __syncthreads();

  int buf = 0;
  for (int kt = 0; kt < NT; kt++) {
    if (kt + 1 < NT) STAGE(kt + 1, buf ^ 1);   // flies under compute
    const bool act0 = (kt <= kd0);             // wave-uniform
    const ushort* Kb = &Ks[buf][0];
    const ushort* Vb = &Vts[buf][0];

    // QK^T swapped: st[mi][ni][r] = S^T[k = kt*64+ni*16+quad*4+r][q = qB+lrow]
    f4v st[2][4];
#pragma unroll
    for (int mi = 0; mi < 2; mi++)
#pragma unroll
      for (int ni = 0; ni < 4; ni++) st[mi][ni] = (f4v){0.f, 0.f, 0.f, 0.f};
    __builtin_amdgcn_s_setprio(1);
#pragma unroll
    for (int kk = 0; kk < 2; kk++) {
      const int ch = (kk * 4 + quad) ^ swl;
#pragma unroll
      for (int ni = 0; ni < 4; ni++) {
        s8v kf = *(const s8v*)&Kb[(ni * 16 + lrow) * 64 + ch * 8];
        st[1][ni] = __builtin_amdgcn_mfma_f32_16x16x32_bf16(kf, qf[1][kk], st[1][ni], 0, 0, 0);
        if (act0)
          st[0][ni] = __builtin_amdgcn_mfma_f32_16x16x32_bf16(kf, qf[0][kk], st[0][ni], 0, 0, 0);
      }
    }
    __builtin_amdgcn_s_setprio(0);

    // softmax per mi; P -> per-wave LDS (transposed write: row q=lrow)
    float alr[2][4];
#pragma unroll
    for (int mi = 0; mi < 2; mi++) {
      if (mi == 0 && !act0) continue;
      const int qB = mi ? qB1 : qB0;
      if (kt == (mi ? kd1 : kd0)) {   // diagonal tile: mask k > q
        int qrow = qB + lrow;
#pragma unroll
        for (int ni = 0; ni < 4; ni++) {
          int kc0 = kt * 64 + ni * 16 + quad * 4;
#pragma unroll
          for (int r = 0; r < 4; r++)
            if (kc0 + r > qrow) st[mi][ni][r] = -INFINITY;
        }
      }
      // row max: 16 in-lane values, then cross-quad
      float bm = st[mi][0][0];
#pragma unroll
      for (int ni = 0; ni < 4; ni++)
#pragma unroll
        for (int r = 0; r < 4; r++) bm = fmaxf(bm, st[mi][ni][r]);
      bm = fmaxf(bm, __shfl_xor(bm, 16));
      bm = fmaxf(bm, __shfl_xor(bm, 32));
      float mn = fmaxf(mr[mi], bm);
      float al = __expf(mr[mi] - mn);
      mr[mi] = mn;
      float bs = 0.f;
#pragma unroll
      for (int ni = 0; ni < 4; ni++) {
        float p0 = __expf(st[mi][ni][0] - mn);
        float p1 = __expf(st[mi][ni][1] - mn);
        float p2 = __expf(st[mi][ni][2] - mn);
        float p3 = __expf(st[mi][ni][3] - mn);
        bs += (p0 + p1) + (p2 + p3);
        ushort4 pk = {f2bf(p0), f2bf(p1), f2bf(p2), f2bf(p3)};
        *(ushort4*)&pw[(mi * 16 + lrow) * 72 + ni * 16 + quad * 4] = pk;
      }
      bs += __shfl_xor(bs, 16);
      bs += __shfl_xor(bs, 32);
      lr[mi] = lr[mi] * al + bs;
      // redistribute al to this lane's o-rows (q-local = quad*4+r)
#pragma unroll
      for (int r = 0; r < 4; r++) alr[mi][r] = __shfl(al, (lane & 48) + quad * 4 + r);
#pragma unroll
      for (int di = 0; di < 4; di++)
#pragma unroll
        for (int r = 0; r < 4; r++) o[mi][di][r] *= alr[mi][r];
    }

    // PV: P as A-frag (wave-local LDS roundtrip), V as B-frag (swizzled)
    __builtin_amdgcn_s_setprio(1);
#pragma unroll
    for (int kk = 0; kk < 2; kk++) {
      const int ch = (kk * 4 + quad) ^ swl;
      s8v pf1 = *(const s8v*)&pw[(16 + lrow) * 72 + kk * 32 + quad * 8];
      if (act0) {
        s8v pf0 = *(const s8v*)&pw[lrow * 72 + kk * 32 + quad * 8];
#pragma unroll
        for (int di = 0; di < 4; di++) {
          s8v vf = *(const s8v*)&Vb[(di * 16 + lrow) * 64 + ch * 8];
          o[1][di] = __builtin_amdgcn_mfma_f32_16x16x32_bf16(pf1, vf, o[1][di], 0, 0, 0);
          o[0][di] = __builtin_amdgcn_mfma_f32_16x16x32_bf16(pf0, vf, o[0][di], 0, 0, 0);
        }
      } else {
#pragma unroll
        for (int di = 0; di < 4; di++) {
          s8v vf = *(const s8v*)&Vb[(di * 16 + lrow) * 64 + ch * 8];
          o[1][di] = __builtin_amdgcn_mfma_f32_16x16x32_bf16(pf1, vf, o[1][di], 0, 0, 0);
        }
      }
    }
    __builtin_amdgcn_s_setprio(0);

    __syncthreads();   // drains staging vmcnt + all waves done reading buf
    buf ^= 1;
  }

  // normalize: lr lives at lanes with lrow == q-local; redistribute to o-rows
  float inv[2][4];
#pragma unroll
  for (int mi = 0; mi < 2; mi++)
#pragma unroll
    for (int r = 0; r < 4; r++)
      inv[mi][r] = 1.0f / __shfl(lr[mi], (lane & 48) + quad * 4 + r);

#pragma unroll
  for (int mi = 0; mi < 2; mi++)
#pragma unroll
    for (int di = 0; di < 4; di++)
#pragma unroll
      for (int r = 0; r < 4; r++)
        pw[(mi * 16 + quad * 4 + r) * 72 + di * 16 + lrow] = f2bf(o[mi][di][r] * inv[mi][r]);

#pragma unroll
  for (int i = 0; i < 4; i++) {
    int c = i * 64 + lane;
    int row = c >> 3, cc = c & 7;
    uint4 val = *(const uint4*)&pw[row * 72 + cc * 8];
    int q = ((row >> 4) ? qB1 : qB0) + (row & 15);
    size_t off = ((size_t)b * S_ + q) * E_ + h * 64 + cc * 8;
    *(uint4*)&AO[off] = val;
  }
}

// ---------------- launch ----------------
extern "C" void kernel_launch(void* const* d_in, const int* in_sizes, int n_in,
                              void* d_out, int out_size, void* d_ws, size_t ws_size,
                              hipStream_t stream) {
  const float* X = (const float*)d_in[0];
  const float* Wq = (const float*)d_in[1];
  const float* Wk = (const float*)d_in[2];
  const float* Wv = (const float*)d_in[3];
  const float* Wo = (const float*)d_in[4];
  const float* bo = (const float*)d_in[5];
  float* out = (float*)d_out;

  // ws layout (bytes). AO aliases Xb (Xb dead after QKV GEMM). Total ~277 MB.
  char* ws = (char*)d_ws;
  ushort* Xb = (ushort*)(ws);                      //  67,108,864
  ushort* Wqkvt = (ushort*)(ws + 67108864);        //   6,291,456 (Wq^T|Wk^T|Wv^T)
  ushort* Wot = (ushort*)(ws + 73400320);          //   2,097,152
  ushort* Qb = (ushort*)(ws + 75497472);           //  67,108,864
  ushort* Kb = (ushort*)(ws + 142606336);          //  67,108,864
  ushort* Vtb = (ushort*)(ws + 209715200);         //  67,108,864 ([bh][d][s])
  ushort* AO = Xb;

  convertx<<<32768, 256, 0, stream>>>(X, Xb);
  transpose_w<<<dim3(32, 32), 256, 0, stream>>>(Wq, Wqkvt);
  transpose_w<<<dim3(32, 32), 256, 0, stream>>>(Wk, Wqkvt + 1024 * 1024);
  transpose_w<<<dim3(32, 32), 256, 0, stream>>>(Wv, Wqkvt + 2 * 1024 * 1024);
  transpose_w<<<dim3(32, 32), 256, 0, stream>>>(Wo, Wot);

  gemm_qkv<<<1536, 512, 0, stream>>>(Xb, Wqkvt, Qb, Kb, Vtb);

  attn_kernel<<<dim3(4, 1024), 256, 0, stream>>>(Qb, Kb, Vtb, AO);

  gemm_o<<<512, 512, 0, stream>>>(AO, Wot, out, bo);
}

// Round 6
// 614.084 us; speedup vs baseline: 1.0424x; 1.0199x over previous
//
#include <hip/hip_runtime.h>
#include <hip/hip_bf16.h>
#include <cstdint>
#include <cstddef>

// Problem constants
#define B_ 64
#define S_ 512
#define E_ 1024
#define H_ 16
#define D_ 64

typedef __attribute__((ext_vector_type(8))) short s8v;   // 8 bf16 = 4 VGPRs (A/B frag)
typedef __attribute__((ext_vector_type(4))) float f4v;   // C/D frag

__device__ __forceinline__ ushort f2bf(float f) {
  uint32_t u = __builtin_bit_cast(uint32_t, f);
  u += 0x7fffu + ((u >> 16) & 1u);   // RNE
  return (ushort)(u >> 16);
}

// async global->LDS, 16B per lane. LDS dest must be wave-uniform base + lane*16.
__device__ __forceinline__ void async_cp16(const void* g, void* l) {
  __builtin_amdgcn_global_load_lds(
      (const __attribute__((address_space(1))) unsigned int*)g,
      (__attribute__((address_space(3))) unsigned int*)(uintptr_t)l,
      16, 0, 0);
}

// ---------------- fp32 -> bf16 convert (X) ----------------
__global__ __launch_bounds__(256) void convertx(const float* __restrict__ X,
                                                ushort* __restrict__ Y) {
  size_t i = ((size_t)blockIdx.x * 256 + threadIdx.x) * 4;
  float4 v = *(const float4*)(X + i);
  uint2 p;
  p.x = (uint32_t)f2bf(v.x) | ((uint32_t)f2bf(v.y) << 16);
  p.y = (uint32_t)f2bf(v.z) | ((uint32_t)f2bf(v.w) << 16);
  *(uint2*)(Y + i) = p;
}

// ---------------- W (ExE fp32) -> Wt (ExE bf16, transposed) ----------------
__global__ __launch_bounds__(256) void transpose_w(const float* __restrict__ W,
                                                   ushort* __restrict__ Wt) {
  __shared__ ushort T[32][33];
  int x = threadIdx.x & 31, y = threadIdx.x >> 5;  // 32 x 8
  int c0 = blockIdx.x * 32;  // col base (n)
  int r0 = blockIdx.y * 32;  // row base (k)
#pragma unroll
  for (int i = 0; i < 4; i++) {
    int r = y + i * 8;
    T[x][r] = f2bf(W[(size_t)(r0 + r) * E_ + c0 + x]);  // coalesced read
  }
  __syncthreads();
#pragma unroll
  for (int i = 0; i < 4; i++) {
    int r = y + i * 8;
    Wt[(size_t)(c0 + r) * E_ + r0 + x] = T[r][x];  // coalesced write
  }
}

// ====== 256x256 4-phase GEMM core, K-half staging + counted vmcnt (T3+T4) ======
// C = A (MxK) * Bt^T (NxK), K = 1024, BK = 64 (2 K-halves of 32). 512 thr = 8 waves
// (2M x 4N), per-wave 128x64, acc[8][4].
// LDS per operand: [2 buf][2 kh][256 rows][32 cols] bf16, each half 16KB contiguous
// (2 x global_load_lds per half). A at smem[0,32K), B at +32768. Total 128 KiB.
// Banking: slot = quad ^ ((row>>1)&3) -- row-bit0 sets bank-bit4 (64B rows), so the
// XOR must NOT use row-bit0 (r3's 19.7M-conflict bug). Per 16-lane group every
// (parity,slot) bucket gets exactly 2 lanes -> uniform, same as the [256][64] layout.
// Phase p1/p2 read kh0 only, p3/p4 kh1 only -> K-half regions are phase-local:
//   p1(t): stage Ah1(t+1)->buf^1  (readers p3/p4(t-1): done >=1 barrier ago)
//   p2(t): stage Bh1(t+1)->buf^1  (reader  p3(t-1):    done)            + W1
//   p3(t): stage Ah0(t+2)->buf    (readers p1/p2(t):   done this tile)
//   p4(t): stage Bh0(t+2)->buf    (reader  p1(t):      done)            + W2
// All stage placements race-free by barrier ordering (no latency margins needed).
// Waits (counted, never drain the newest 8 loads):
//   W1 end-p2: vmcnt(8) => kh1(t) landed   [issued p1/p2(t-1), 6-phase slack]
//   W2 end-p4: vmcnt(8) => kh0(t+1) landed [issued p3/p4(t-1), 6-phase slack]
// 6 phases ~ >=1000 cyc >= HBM latency (~900) -> stall-free steady state.
// Prologue: 6 halves, vmcnt(8). Epilogue: stages guarded (p1/p2: t<15, p3/p4: t<14);
// W2@t=14 -> vmcnt(4); W1@t=15 -> vmcnt(0); W2@t=15 skipped.
__device__ __forceinline__ void gemm256_core(const ushort* __restrict__ A,
                                             const ushort* __restrict__ Bt,
                                             int m0, int n0, ushort* smem,
                                             f4v acc[8][4]) {
  const int tid = threadIdx.x;
  const int wave = tid >> 6, lane = tid & 63;
  const int wm = wave >> 2, wn = wave & 3;
  const int lrow = lane & 15, quad = lane >> 4;
  const int slot8 = (quad ^ ((lrow >> 1) & 3)) * 8;       // bank-safe (no row-bit0)
  const int arow = (wm * 128 + lrow) * 32 + slot8;
  const int brow = (wn * 64 + lrow) * 32 + slot8;
  const int srow = tid >> 2;                              // staging row (0..127)
  const int c8 = ((tid & 3) ^ ((tid >> 3) & 3)) * 8;      // inverse-swizzled src chunk
  const ushort* Ab = A + (size_t)m0 * E_;
  const ushort* Bb = Bt + (size_t)n0 * E_;

#define AH_(buf, kh) (smem + ((buf) * 2 + (kh)) * 8192)
#define BH_(buf, kh) (smem + 32768 + ((buf) * 2 + (kh)) * 8192)

  // stage one [256][32] K-half: g = tile base (+kh*32 inside), 2 instrs x 8KB
  auto STGH = [&](const ushort* g, int kh, ushort* l) {
#pragma unroll
    for (int i = 0; i < 2; i++)
      async_cp16(g + (size_t)(srow + i * 128) * E_ + kh * 32 + c8,
                 l + i * 4096 + tid * 8);
  };

#pragma unroll
  for (int i = 0; i < 8; i++)
#pragma unroll
    for (int j = 0; j < 4; j++) acc[i][j] = (f4v){0.f, 0.f, 0.f, 0.f};

  // prologue: Ah0(0) Bh0(0) Ah1(0) Bh1(0) Ah0(1) Bh0(1); wait oldest 4 (tile0 kh0).
  STGH(Ab, 0, AH_(0, 0));
  STGH(Bb, 0, BH_(0, 0));
  STGH(Ab, 1, AH_(0, 1));
  STGH(Bb, 1, BH_(0, 1));
  STGH(Ab + 64, 0, AH_(1, 0));
  STGH(Bb + 64, 0, BH_(1, 0));
  asm volatile("s_waitcnt vmcnt(8)" ::: "memory");
  __builtin_amdgcn_s_barrier();

  for (int t = 0; t < 16; ++t) {
    const int buf = t & 1;
    const ushort* A0s = AH_(buf, 0);
    const ushort* A1s = AH_(buf, 1);
    const ushort* B0s = BH_(buf, 0);
    const ushort* B1s = BH_(buf, 1);
    s8v a[4], b[4];

    // ---- p1: kh0, m0-3; stage Ah1(t+1) ----
#pragma unroll
    for (int i = 0; i < 4; i++) a[i] = *(const s8v*)(A0s + arow + i * 512);
#pragma unroll
    for (int n = 0; n < 4; n++) b[n] = *(const s8v*)(B0s + brow + n * 512);
    if (t < 15) STGH(Ab + (size_t)(t + 1) * 64, 1, AH_(buf ^ 1, 1));
    __builtin_amdgcn_s_barrier();
    __builtin_amdgcn_s_setprio(1);
#pragma unroll
    for (int i = 0; i < 4; i++)
#pragma unroll
      for (int n = 0; n < 4; n++)
        acc[i][n] = __builtin_amdgcn_mfma_f32_16x16x32_bf16(a[i], b[n], acc[i][n], 0, 0, 0);
    __builtin_amdgcn_s_setprio(0);
    __builtin_amdgcn_s_barrier();

    // ---- p2: kh0, m4-7 (b reused); stage Bh1(t+1); W1 ----
#pragma unroll
    for (int i = 0; i < 4; i++) a[i] = *(const s8v*)(A0s + arow + (4 + i) * 512);
    if (t < 15) STGH(Bb + (size_t)(t + 1) * 64, 1, BH_(buf ^ 1, 1));
    __builtin_amdgcn_s_barrier();
    __builtin_amdgcn_s_setprio(1);
#pragma unroll
    for (int i = 0; i < 4; i++)
#pragma unroll
      for (int n = 0; n < 4; n++)
        acc[4 + i][n] = __builtin_amdgcn_mfma_f32_16x16x32_bf16(a[i], b[n], acc[4 + i][n], 0, 0, 0);
    __builtin_amdgcn_s_setprio(0);
    if (t < 15) {
      asm volatile("s_waitcnt vmcnt(8)" ::: "memory");  // kh1(t) landed
    } else {
      asm volatile("s_waitcnt vmcnt(0)" ::: "memory");  // kh1(15) landed (final)
    }
    __builtin_amdgcn_s_barrier();

    // ---- p3: kh1, m0-3; stage Ah0(t+2) ----
#pragma unroll
    for (int i = 0; i < 4; i++) a[i] = *(const s8v*)(A1s + arow + i * 512);
#pragma unroll
    for (int n = 0; n < 4; n++) b[n] = *(const s8v*)(B1s + brow + n * 512);
    if (t < 14) STGH(Ab + (size_t)(t + 2) * 64, 0, AH_(buf, 0));
    __builtin_amdgcn_s_barrier();
    __builtin_amdgcn_s_setprio(1);
#pragma unroll
    for (int i = 0; i < 4; i++)
#pragma unroll
      for (int n = 0; n < 4; n++)
        acc[i][n] = __builtin_amdgcn_mfma_f32_16x16x32_bf16(a[i], b[n], acc[i][n], 0, 0, 0);
    __builtin_amdgcn_s_setprio(0);
    __builtin_amdgcn_s_barrier();

    // ---- p4: kh1, m4-7 (b reused); stage Bh0(t+2); W2 ----
#pragma unroll
    for (int i = 0; i < 4; i++) a[i] = *(const s8v*)(A1s + arow + (4 + i) * 512);
    if (t < 14) STGH(Bb + (size_t)(t + 2) * 64, 0, BH_(buf, 0));
    __builtin_amdgcn_s_barrier();
    __builtin_amdgcn_s_setprio(1);
#pragma unroll
    for (int i = 0; i < 4; i++)
#pragma unroll
      for (int n = 0; n < 4; n++)
        acc[4 + i][n] = __builtin_amdgcn_mfma_f32_16x16x32_bf16(a[i], b[n], acc[4 + i][n], 0, 0, 0);
    __builtin_amdgcn_s_setprio(0);
    if (t < 14) {
      asm volatile("s_waitcnt vmcnt(8)" ::: "memory");  // kh0(t+1) landed
    } else if (t == 14) {
      asm volatile("s_waitcnt vmcnt(4)" ::: "memory");  // kh0(15) landed
    }
    __builtin_amdgcn_s_barrier();
  }
#undef AH_
#undef BH_
}

// ---------------- fused QKV GEMM: [32768,1024] x [3072,1024]^T ----------------
// Bt rows 0..1023 = Wq^T, 1024..2047 = Wk^T, 2048..3071 = Wv^T.
// 1536 blocks (12 n-tiles x 128 m-tiles), XCD-swizzled, n fastest.
// Q,K written [bh][s][d]; V written TRANSPOSED [bh][d][s].
__global__ __launch_bounds__(512, 2) void gemm_qkv(
    const ushort* __restrict__ A, const ushort* __restrict__ Bt,
    ushort* __restrict__ Qo, ushort* __restrict__ Ko, ushort* __restrict__ Vt) {
  __shared__ __align__(16) ushort smem[65536];  // 128 KiB
  const int orig = blockIdx.x;
  const int swz = (orig & 7) * 192 + (orig >> 3);  // 1536 % 8 == 0 -> bijective
  const int ntile = swz % 12, mtile = swz / 12;
  const int n0 = ntile * 256, m0 = mtile * 256;

  f4v acc[8][4];
  gemm256_core(A, Bt, m0, n0, smem, acc);

  const int tid = threadIdx.x;
  const int wave = tid >> 6, lane = tid & 63;
  const int wm = wave >> 2, wn = wave & 3;
  const int lrow = lane & 15, quad = lane >> 4;
  const int proj = n0 >> 10;       // 0=Q 1=K 2=V (uniform per block)
  const int np0 = n0 & 1023;
  const int hb = np0 >> 6;         // head base (0,4,8,12)
  const int bb = m0 >> 9, s0 = m0 & 511;

  if (proj < 2) {
    ushort* C = proj == 0 ? Qo : Ko;
    // two m-half steps: stage [128][264] rows, then 16B merged-head stores
#pragma unroll
    for (int h = 0; h < 2; h++) {
#pragma unroll
      for (int mf = 0; mf < 4; mf++)
#pragma unroll
        for (int n = 0; n < 4; n++)
#pragma unroll
          for (int r = 0; r < 4; r++)
            smem[(wm * 64 + mf * 16 + quad * 4 + r) * 264 + wn * 64 + n * 16 + lrow] =
                f2bf(acc[h * 4 + mf][n][r]);
      __syncthreads();
#pragma unroll
      for (int j = 0; j < 8; j++) {
        int chunk = j * 512 + tid;
        int pr = chunk >> 5, cc = chunk & 31;
        int s = s0 + (pr >> 6) * 128 + h * 64 + (pr & 63);
        int hd = hb + (cc >> 3);
        size_t off = (((size_t)bb * H_ + hd) * S_ + s) * D_ + (cc & 7) * 8;
        *(uint4*)&C[off] = *(const uint4*)&smem[pr * 264 + cc * 8];
      }
      if (h == 0) __syncthreads();
    }
  } else {
    // V transposed: two wm-half steps; stage [256 d][136] (s cols), 16B stores
#pragma unroll
    for (int w = 0; w < 2; w++) {
      if (wm == w) {
#pragma unroll
        for (int m = 0; m < 8; m++)
#pragma unroll
          for (int n = 0; n < 4; n++) {
            ushort4 pk;
            pk.x = f2bf(acc[m][n][0]);
            pk.y = f2bf(acc[m][n][1]);
            pk.z = f2bf(acc[m][n][2]);
            pk.w = f2bf(acc[m][n][3]);
            *(ushort4*)&smem[(wn * 64 + n * 16 + lrow) * 136 + m * 16 + quad * 4] = pk;
          }
      }
      __syncthreads();
#pragma unroll
      for (int j = 0; j < 8; j++) {
        int chunk = j * 512 + tid;
        int dr = chunk >> 4, cc = chunk & 15;
        int hd = hb + (dr >> 6), d = dr & 63;
        size_t off = (((size_t)bb * H_ + hd) * D_ + d) * S_ + s0 + w * 128 + cc * 8;
        *(uint4*)&Vt[off] = *(const uint4*)&smem[dr * 136 + cc * 8];
      }
      if (w == 0) __syncthreads();
    }
  }
}

// ---------------- O GEMM: fp32 out + bias ----------------
// 512 blocks (4 n-tiles x 128 m-tiles), XCD-swizzled.
__global__ __launch_bounds__(512, 2) void gemm_o(
    const ushort* __restrict__ A, const ushort* __restrict__ Bt,
    float* __restrict__ C, const float* __restrict__ bias) {
  __shared__ __align__(16) ushort smem[65536];
  const int orig = blockIdx.x;
  const int swz = (orig & 7) * 64 + (orig >> 3);  // 512 % 8 == 0 -> bijective
  const int ntile = swz & 3, mtile = swz >> 2;
  const int n0 = ntile * 256, m0 = mtile * 256;

  f4v acc[8][4];
  gemm256_core(A, Bt, m0, n0, smem, acc);

  const int tid = threadIdx.x;
  const int wave = tid >> 6, lane = tid & 63;
  const int wm = wave >> 2, wn = wave & 3;
  const int lrow = lane & 15, quad = lane >> 4;
#pragma unroll
  for (int n = 0; n < 4; n++) {
    int col = n0 + wn * 64 + n * 16 + lrow;
    float bv = bias[col];
#pragma unroll
    for (int m = 0; m < 8; m++) {
      int row = m0 + wm * 128 + m * 16 + quad * 4;
#pragma unroll
      for (int r = 0; r < 4; r++)
        C[(size_t)(row + r) * E_ + col] = acc[m][n][r] + bv;
    }
  }
}

// ---------------- fused causal flash attention v3 ----------------
// grid: (4, B*H). block: 256 (4 waves). Block qp pairs q-tiles (qp, 7-qp):
// wave w owns 16-row m-tile mi=0 at qp*64+w*16 and mi=1 at (7-qp)*64+w*16
// -> every wave does exactly 9 mi-tile-units (causal-balanced).
// K/V cooperatively staged to double-buffered LDS; stage t+1 issued BEFORE
// compute(t), single __syncthreads (vmcnt drain) after compute -> loads fly
// under compute (T3-lite 2-phase).
// QK^T SWAPPED (mfma(K,Q)): S^T[k=quad*4+r + ni*16][q=lrow] -> row stats are
// 15 in-lane ops + 2 shuffles; m/l per-lane scalars. P written transposed to
// per-wave LDS (layout identical to before for the PV A-frag read).
__global__ __launch_bounds__(256, 3) void attn_kernel(
    const ushort* __restrict__ Qg, const ushort* __restrict__ Kg,
    const ushort* __restrict__ Vtg, ushort* __restrict__ AO) {
  __shared__ __align__(16) ushort Ks[2][64 * 64];
  __shared__ __align__(16) ushort Vts[2][64 * 64];   // [d][s_local]
  __shared__ __align__(16) ushort Ps[4][32 * 72];    // per-wave P / O staging

  const int qp = blockIdx.x;            // 0..3 -> q-tiles qp and 7-qp
  const int bh = blockIdx.y;            // 0..1023
  const int b = bh >> 4, h = bh & 15;
  const int tid = threadIdx.x, wave = tid >> 6, lane = tid & 63;
  const int lrow = lane & 15, quad = lane >> 4;
  const int swl = lrow & 7;
  const size_t base = (size_t)bh * (S_ * D_);
  const int qB0 = qp * 64 + wave * 16;        // mi=0 q-rows
  const int qB1 = (7 - qp) * 64 + wave * 16;  // mi=1 q-rows
  const int kd0 = qp, kd1 = 7 - qp;           // per-mi diagonal K-tile
  const int NT = kd1 + 1;

  // Q fragments straight from global (B-frag: col=q-row=lrow, k=quad*8 in 32)
  s8v qf[2][2];
#pragma unroll
  for (int kk = 0; kk < 2; kk++) {
    qf[0][kk] = *(const s8v*)(Qg + base + (size_t)(qB0 + lrow) * 64 + kk * 32 + quad * 8);
    qf[1][kk] = *(const s8v*)(Qg + base + (size_t)(qB1 + lrow) * 64 + kk * 32 + quad * 8);
  }

  f4v o[2][4];
#pragma unroll
  for (int mi = 0; mi < 2; mi++)
#pragma unroll
    for (int di = 0; di < 4; di++) o[mi][di] = (f4v){0.f, 0.f, 0.f, 0.f};
  float mr[2] = {-INFINITY, -INFINITY};   // per-lane scalar (q-row = lrow)
  float lr[2] = {0.f, 0.f};

  ushort* pw = &Ps[wave][0];

  auto STAGE = [&](int kt, int bf) {
#pragma unroll
    for (int i = 0; i < 2; i++) {
      int c = i * 256 + tid;
      int r = c >> 3, cc = c & 7;
      int sc = cc ^ (r & 7);
      async_cp16(Kg + base + (size_t)(kt * 64 + r) * 64 + sc * 8, (void*)&Ks[bf][c * 8]);
    }
#pragma unroll
    for (int i = 0; i < 2; i++) {
      int c = i * 256 + tid;
      int d = c >> 3, cc = c & 7;
      int sc = cc ^ (d & 7);
      async_cp16(Vtg + base + (size_t)d * S_ + kt * 64 + sc * 8, (void*)&Vts[bf][c * 8]);
    }
  };

  STAGE(0, 0);
  __syncthreads();

  int buf = 0;
  for (int kt = 0; kt < NT; kt++) {
    if (kt + 1 < NT) STAGE(kt + 1, buf ^ 1);   // flies under compute
    const bool act0 = (kt <= kd0);             // wave-uniform
    const ushort* Kb = &Ks[buf][0];
    const ushort* Vb = &Vts[buf][0];

    // QK^T swapped: st[mi][ni][r] = S^T[k = kt*64+ni*16+quad*4+r][q = qB+lrow]
    f4v st[2][4];
#pragma unroll
    for (int mi = 0; mi < 2; mi++)
#pragma unroll
      for (int ni = 0; ni < 4; ni++) st[mi][ni] = (f4v){0.f, 0.f, 0.f, 0.f};
    __builtin_amdgcn_s_setprio(1);
#pragma unroll
    for (int kk = 0; kk < 2; kk++) {
      const int ch = (kk * 4 + quad) ^ swl;
#pragma unroll
      for (int ni = 0; ni < 4; ni++) {
        s8v kf = *(const s8v*)&Kb[(ni * 16 + lrow) * 64 + ch * 8];
        st[1][ni] = __builtin_amdgcn_mfma_f32_16x16x32_bf16(kf, qf[1][kk], st[1][ni], 0, 0, 0);
        if (act0)
          st[0][ni] = __builtin_amdgcn_mfma_f32_16x16x32_bf16(kf, qf[0][kk], st[0][ni], 0, 0, 0);
      }
    }
    __builtin_amdgcn_s_setprio(0);

    // softmax per mi; P -> per-wave LDS (transposed write: row q=lrow)
    float alr[2][4];
#pragma unroll
    for (int mi = 0; mi < 2; mi++) {
      if (mi == 0 && !act0) continue;
      const int qB = mi ? qB1 : qB0;
      if (kt == (mi ? kd1 : kd0)) {   // diagonal tile: mask k > q
        int qrow = qB + lrow;
#pragma unroll
        for (int ni = 0; ni < 4; ni++) {
          int kc0 = kt * 64 + ni * 16 + quad * 4;
#pragma unroll
          for (int r = 0; r < 4; r++)
            if (kc0 + r > qrow) st[mi][ni][r] = -INFINITY;
        }
      }
      // row max: 16 in-lane values, then cross-quad
      float bm = st[mi][0][0];
#pragma unroll
      for (int ni = 0; ni < 4; ni++)
#pragma unroll
        for (int r = 0; r < 4; r++) bm = fmaxf(bm, st[mi][ni][r]);
      bm = fmaxf(bm, __shfl_xor(bm, 16));
      bm = fmaxf(bm, __shfl_xor(bm, 32));
      float mn = fmaxf(mr[mi], bm);
      float al = __expf(mr[mi] - mn);
      mr[mi] = mn;
      float bs = 0.f;
#pragma unroll
      for (int ni = 0; ni < 4; ni++) {
        float p0 = __expf(st[mi][ni][0] - mn);
        float p1 = __expf(st[mi][ni][1] - mn);
        float p2 = __expf(st[mi][ni][2] - mn);
        float p3 = __expf(st[mi][ni][3] - mn);
        bs += (p0 + p1) + (p2 + p3);
        ushort4 pk = {f2bf(p0), f2bf(p1), f2bf(p2), f2bf(p3)};
        *(ushort4*)&pw[(mi * 16 + lrow) * 72 + ni * 16 + quad * 4] = pk;
      }
      bs += __shfl_xor(bs, 16);
      bs += __shfl_xor(bs, 32);
      lr[mi] = lr[mi] * al + bs;
      // redistribute al to this lane's o-rows (q-local = quad*4+r)
#pragma unroll
      for (int r = 0; r < 4; r++) alr[mi][r] = __shfl(al, (lane & 48) + quad * 4 + r);
#pragma unroll
      for (int di = 0; di < 4; di++)
#pragma unroll
        for (int r = 0; r < 4; r++) o[mi][di][r] *= alr[mi][r];
    }

    // PV: P as A-frag (wave-local LDS roundtrip), V as B-frag (swizzled)
    __builtin_amdgcn_s_setprio(1);
#pragma unroll
    for (int kk = 0; kk < 2; kk++) {
      const int ch = (kk * 4 + quad) ^ swl;
      s8v pf1 = *(const s8v*)&pw[(16 + lrow) * 72 + kk * 32 + quad * 8];
      if (act0) {
        s8v pf0 = *(const s8v*)&pw[lrow * 72 + kk * 32 + quad * 8];
#pragma unroll
        for (int di = 0; di < 4; di++) {
          s8v vf = *(const s8v*)&Vb[(di * 16 + lrow) * 64 + ch * 8];
          o[1][di] = __builtin_amdgcn_mfma_f32_16x16x32_bf16(pf1, vf, o[1][di], 0, 0, 0);
          o[0][di] = __builtin_amdgcn_mfma_f32_16x16x32_bf16(pf0, vf, o[0][di], 0, 0, 0);
        }
      } else {
#pragma unroll
        for (int di = 0; di < 4; di++) {
          s8v vf = *(const s8v*)&Vb[(di * 16 + lrow) * 64 + ch * 8];
          o[1][di] = __builtin_amdgcn_mfma_f32_16x16x32_bf16(pf1, vf, o[1][di], 0, 0, 0);
        }
      }
    }
    __builtin_amdgcn_s_setprio(0);

    __syncthreads();   // drains staging vmcnt + all waves done reading buf
    buf ^= 1;
  }

  // normalize: lr lives at lanes with lrow == q-local; redistribute to o-rows
  float inv[2][4];
#pragma unroll
  for (int mi = 0; mi < 2; mi++)
#pragma unroll
    for (int r = 0; r < 4; r++)
      inv[mi][r] = 1.0f / __shfl(lr[mi], (lane & 48) + quad * 4 + r);

#pragma unroll
  for (int mi = 0; mi < 2; mi++)
#pragma unroll
    for (int di = 0; di < 4; di++)
#pragma unroll
      for (int r = 0; r < 4; r++)
        pw[(mi * 16 + quad * 4 + r) * 72 + di * 16 + lrow] = f2bf(o[mi][di][r] * inv[mi][r]);

#pragma unroll
  for (int i = 0; i < 4; i++) {
    int c = i * 64 + lane;
    int row = c >> 3, cc = c & 7;
    uint4 val = *(const uint4*)&pw[row * 72 + cc * 8];
    int q = ((row >> 4) ? qB1 : qB0) + (row & 15);
    size_t off = ((size_t)b * S_ + q) * E_ + h * 64 + cc * 8;
    *(uint4*)&AO[off] = val;
  }
}

// ---------------- launch ----------------
extern "C" void kernel_launch(void* const* d_in, const int* in_sizes, int n_in,
                              void* d_out, int out_size, void* d_ws, size_t ws_size,
                              hipStream_t stream) {
  const float* X = (const float*)d_in[0];
  const float* Wq = (const float*)d_in[1];
  const float* Wk = (const float*)d_in[2];
  const float* Wv = (const float*)d_in[3];
  const float* Wo = (const float*)d_in[4];
  const float* bo = (const float*)d_in[5];
  float* out = (float*)d_out;

  // ws layout (bytes). AO aliases Xb (Xb dead after QKV GEMM). Total ~277 MB.
  char* ws = (char*)d_ws;
  ushort* Xb = (ushort*)(ws);                      //  67,108,864
  ushort* Wqkvt = (ushort*)(ws + 67108864);        //   6,291,456 (Wq^T|Wk^T|Wv^T)
  ushort* Wot = (ushort*)(ws + 73400320);          //   2,097,152
  ushort* Qb = (ushort*)(ws + 75497472);           //  67,108,864
  ushort* Kb = (ushort*)(ws + 142606336);          //  67,108,864
  ushort* Vtb = (ushort*)(ws + 209715200);         //  67,108,864 ([bh][d][s])
  ushort* AO = Xb;

  convertx<<<32768, 256, 0, stream>>>(X, Xb);
  transpose_w<<<dim3(32, 32), 256, 0, stream>>>(Wq, Wqkvt);
  transpose_w<<<dim3(32, 32), 256, 0, stream>>>(Wk, Wqkvt + 1024 * 1024);
  transpose_w<<<dim3(32, 32), 256, 0, stream>>>(Wv, Wqkvt + 2 * 1024 * 1024);
  transpose_w<<<dim3(32, 32), 256, 0, stream>>>(Wo, Wot);

  gemm_qkv<<<1536, 512, 0, stream>>>(Xb, Wqkvt, Qb, Kb, Vtb);

  attn_kernel<<<dim3(4, 1024), 256, 0, stream>>>(Qb, Kb, Vtb, AO);

  gemm_o<<<512, 512, 0, stream>>>(AO, Wot, out, bo);
}